// Round 7
// baseline (373.389 us; speedup 1.0000x reference)
//
#include <hip/hip_runtime.h>
#include <math.h>

#define BINS 2048
#define UPSAMPLE 128

// Fine grid: width 1/2048. histc range endpoints trunc(cmin)/trunc(cmax) are
// INTEGERS, so every final bin edge is an integer multiple of 1/2048 -> a
// fixed fine histogram (built before min/max is known) coarsens exactly.
#define LWIN 16384              // fine bins covered by LDS window: [-4, 4)
#define LHALF 8192
#define LWORDS 4096             // packed: 4 x u8 counters per u32 word
#define WIDE_N 524288           // wide grid bins, covers [-128, 128)
#define WIDE_HALF 262144
#define NBLK 1024               // pass-1 blocks (4 per CU)
#define NTHR 512
#define RGRP 32                 // reduce: 32 partials per group, 32 groups

// d_ws layout (uint32 units):
//   [0, WIDE_N)                 wide fine grid (plain u32 counts)
//   [WIDE_N], [WIDE_N+1]        encoded running min / max
//   [PART_OFF, +NBLK*LWORDS)    per-block packed partial fine hists
#define MM_OFF   WIDE_N
#define PART_OFF (WIDE_N + 16)

typedef float f32x4 __attribute__((ext_vector_type(4)));

__device__ __forceinline__ unsigned enc_f32(float f) {
    unsigned u = __float_as_uint(f);
    return (u & 0x80000000u) ? ~u : (u | 0x80000000u);
}
__device__ __forceinline__ float dec_f32(unsigned e) {
    unsigned u = (e & 0x80000000u) ? (e ^ 0x80000000u) : ~e;
    return __uint_as_float(u);
}

__global__ void __launch_bounds__(256) hq_init(unsigned* ws) {
    long i = (long)blockIdx.x * blockDim.x + threadIdx.x;   // 131072 threads
    ((uint4*)ws)[i] = make_uint4(0u, 0u, 0u, 0u);           // zero wide grid
    if (i == 0) {
        ws[MM_OFF]     = 0xFFFFFFFFu;  // min sentinel
        ws[MM_OFF + 1] = 0u;           // max sentinel
    }
}

__device__ __forceinline__ void fine_add(float c, float& vmin, float& vmax,
                                         unsigned* sh, unsigned* ws) {
    vmin = fminf(vmin, c);
    vmax = fmaxf(vmax, c);
    float t = floorf(c * 2048.0f);                 // EXACT: pow2 multiply
    t = fminf(fmaxf(t, (float)(-WIDE_HALF)), (float)(WIDE_HALF - 1));
    int fi = (int)t;
    int li = fi + LHALF;
    if ((unsigned)li < (unsigned)LWIN) {
        atomicAdd(&sh[li >> 2], 1u << ((li & 3) << 3));  // packed u8 x4
    } else {
        atomicAdd(&ws[fi + WIDE_HALF], 1u);              // rare: |x| >= 4
    }
}

__global__ void __launch_bounds__(NTHR) hq_pass1(const f32x4* __restrict__ x4, long n4,
                                                 const float* __restrict__ xt, int ntail,
                                                 unsigned* __restrict__ ws) {
    __shared__ unsigned sh[LWORDS];
    __shared__ float smin[NTHR / 64], smax[NTHR / 64];
    for (int i = threadIdx.x; i < LWORDS; i += NTHR) sh[i] = 0u;
    __syncthreads();

    float vmin = INFINITY, vmax = -INFINITY;
    long i0 = (long)blockIdx.x * NTHR + threadIdx.x;
    long stride = (long)NBLK * NTHR;
    for (long i = i0; i < n4; i += stride) {
        f32x4 v = __builtin_nontemporal_load(&x4[i]);
        fine_add(v.x, vmin, vmax, sh, ws);
        fine_add(v.y, vmin, vmax, sh, ws);
        fine_add(v.z, vmin, vmax, sh, ws);
        fine_add(v.w, vmin, vmax, sh, ws);
    }
    if (blockIdx.x == 0 && threadIdx.x < ntail) {
        fine_add(xt[threadIdx.x], vmin, vmax, sh, ws);
    }

    #pragma unroll
    for (int off = 32; off; off >>= 1) {
        vmin = fminf(vmin, __shfl_xor(vmin, off));
        vmax = fmaxf(vmax, __shfl_xor(vmax, off));
    }
    int wid = threadIdx.x >> 6, lane = threadIdx.x & 63;
    if (lane == 0) { smin[wid] = vmin; smax[wid] = vmax; }
    __syncthreads();   // also fences all LDS hist atomics

    if (threadIdx.x == 0) {
        float bmin = INFINITY, bmax = -INFINITY;
        #pragma unroll
        for (int w = 0; w < NTHR / 64; ++w) {
            bmin = fminf(bmin, smin[w]);
            bmax = fmaxf(bmax, smax[w]);
        }
        atomicMin(&ws[MM_OFF], enc_f32(bmin));
        atomicMax(&ws[MM_OFF + 1], enc_f32(bmax));
    }

    unsigned* part = ws + PART_OFF + (size_t)blockIdx.x * LWORDS;
    for (int i = threadIdx.x; i < LWORDS; i += NTHR) part[i] = sh[i];
}

// Sum NBLK packed partials per word, unpack 4 x u8, merge into the wide grid.
// grid = 512 blocks x 256: block -> (word chunk c of 16, partial group g of 32)
__global__ void __launch_bounds__(256) hq_reduce(unsigned* __restrict__ ws) {
    int c = blockIdx.x & 15;          // 16 chunks of 256 words = 4096
    int g = blockIdx.x >> 4;          // 32 groups of RGRP partials
    int w = c * 256 + threadIdx.x;    // packed word index in [0, LWORDS)
    const unsigned* p = ws + PART_OFF + w + (size_t)g * RGRP * LWORDS;
    unsigned s0 = 0, s1 = 0, s2 = 0, s3 = 0;
    #pragma unroll 8
    for (int b = 0; b < RGRP; ++b) {
        unsigned v = p[(size_t)b * LWORDS];
        s0 += v & 0xFFu;
        s1 += (v >> 8) & 0xFFu;
        s2 += (v >> 16) & 0xFFu;
        s3 += v >> 24;
    }
    unsigned base = WIDE_HALF - LHALF + 4 * w;
    if (s0) atomicAdd(&ws[base],     s0);
    if (s1) atomicAdd(&ws[base + 1], s1);
    if (s2) atomicAdd(&ws[base + 2], s2);
    if (s3) atomicAdd(&ws[base + 3], s3);
}

__global__ void __launch_bounds__(1024) hq_finalize(float* __restrict__ out,
                                                    const float* __restrict__ old_hist,
                                                    const float* __restrict__ min_val,
                                                    const float* __restrict__ max_val,
                                                    const unsigned* __restrict__ ws) {
    __shared__ float h[BINS];
    __shared__ float sc[2][BINS];
    int t = threadIdx.x;  // 1024 threads, 2 bins each

    float mn = min_val[0], mx = max_val[0];
    float cmin  = fminf(dec_f32(ws[MM_OFF]), mn);
    float cmax0 = fmaxf(dec_f32(ws[MM_OFF + 1]), mx);

    h[t]        = old_hist[t];
    h[t + 1024] = old_hist[t + 1024];
    sc[0][t]        = h[t];
    sc[0][t + 1024] = h[t + 1024];
    __syncthreads();

    // Hillis-Steele inclusive scan over 2048 elements
    int src = 0;
    for (int off = 1; off < BINS; off <<= 1) {
        int dst = src ^ 1;
        #pragma unroll
        for (int k = 0; k < 2; ++k) {
            int i = t + k * 1024;
            float v = sc[src][i];
            if (i >= off) v += sc[src][i - off];
            sc[dst][i] = v;
        }
        __syncthreads();
        src = dst;
    }
    const float* incl = sc[src];

    float hbw = (mx - mn) / (float)(BINS * UPSAMPLE);
    float bw  = (float)BINS * hbw;
    float dr_f = ceilf((cmax0 - cmin) / bw);
    float cmax = cmax0 + (dr_f * bw - (cmax0 - cmin));
    float hmn = truncf(cmin), hmx = truncf(cmax);   // integer-valued
    int dr = (int)dr_f;
    int start_idx = (int)rintf((mn - cmin) / hbw);  // round-half-even = jnp.round
    bool same = (cmin == mn) && (cmax == mx);
    int hmn_i = (int)hmn;
    int range_i = (int)(hmx - hmn);

    #pragma unroll
    for (int k = 0; k < 2; ++k) {
        int i = t + k * 1024;

        // hist_new[i]: sum of range_i fine bins starting at this bin's edge
        float hn = 0.0f;
        if (range_i > 0) {
            long fi0 = (long)hmn_i * 2048 + (long)i * range_i + WIDE_HALF;
            unsigned s = 0;
            for (int r = 0; r < range_i; ++r) {
                long fi = fi0 + r;
                if (fi >= 0 && fi < (long)WIDE_N) s += ws[fi];
            }
            hn = (float)s;
        }

        // analytic combine of the old histogram
        float integ_i = 0.0f, integ_p = 0.0f;
        {
            int q = (i + 1) * dr - 1 - start_idx;
            if (q >= 0) {
                int qc = min(q, BINS * UPSAMPLE - 1);
                int j = qc >> 7;
                float pref = (j ? incl[j - 1] : 0.0f) * (float)UPSAMPLE;
                integ_i = pref + ((float)(qc & 127) + 1.0f) * h[j];
            }
        }
        if (i > 0) {
            int q = i * dr - 1 - start_idx;
            if (q >= 0) {
                int qc = min(q, BINS * UPSAMPLE - 1);
                int j = qc >> 7;
                float pref = (j ? incl[j - 1] : 0.0f) * (float)UPSAMPLE;
                integ_p = pref + ((float)(qc & 127) + 1.0f) * h[j];
            }
        }
        float interp = (integ_i - integ_p) * (1.0f / (float)UPSAMPLE);
        out[i] = hn + (same ? h[i] : interp);
    }
    if (t == 0) {
        out[BINS]     = cmin;
        out[BINS + 1] = cmax;
    }
}

extern "C" void kernel_launch(void* const* d_in, const int* in_sizes, int n_in,
                              void* d_out, int out_size, void* d_ws, size_t ws_size,
                              hipStream_t stream) {
    (void)n_in; (void)out_size; (void)ws_size;
    const float* x         = (const float*)d_in[0];
    const float* histogram = (const float*)d_in[1];
    const float* min_val   = (const float*)d_in[2];
    const float* max_val   = (const float*)d_in[3];
    float* out   = (float*)d_out;
    unsigned* ws = (unsigned*)d_ws;

    long n  = (long)in_sizes[0];
    long n4 = n >> 2;
    int ntail = (int)(n & 3);
    const float* xt = x + (n4 << 2);

    hq_init<<<WIDE_N / 4 / 256, 256, 0, stream>>>(ws);
    hq_pass1<<<NBLK, NTHR, 0, stream>>>((const f32x4*)x, n4, xt, ntail, ws);
    hq_reduce<<<16 * RGRP, 256, 0, stream>>>(ws);
    hq_finalize<<<1, 1024, 0, stream>>>(out, histogram, min_val, max_val, ws);
}